// Round 7
// baseline (467.231 us; speedup 1.0000x reference)
//
#include <hip/hip_runtime.h>

#define TW 32
#define TH 32
#define SH 42              // TH + 10 halo rows
#define HPITCH 36          // h-filtered pitch (mult of 4; 36 mod 32 = 4 bank shift)
#define BLOCK 256
#define IMG_W 768
#define IMG_H 768
#define IMG_B 32
#define GX_ (IMG_W / TW)
#define GY_ (IMG_H / TH)
#define NBLOCKS (GX_ * GY_ * IMG_B)   // 18432

// Gaussian window sigma=1.5, ws=11, normalized (f64-computed, f32-cast).
#define W0 0.00102838f
#define W1 0.00759876f
#define W2 0.03600077f
#define W3 0.10936069f
#define W4 0.21300554f
#define W5 0.26601173f

// 8 waves/EU -> 64-VGPR cap. Kernel is written so phase-B live set is ~51
// regs (no temp arrays, no by-pointer helpers) so the cap holds WITHOUT
// scratch spill. Go/no-go counter: WRITE_SIZE must be ~0.6 MB, not ~400 MB.
__global__ __launch_bounds__(BLOCK, 8) void ssim_tile_kernel(
    const float* __restrict__ pred, const float* __restrict__ yin,
    float* __restrict__ partial)
{
    constexpr float GW[11] = {W0, W1, W2, W3, W4, W5, W4, W3, W2, W1, W0};

    __shared__ __align__(16) float Hb[3][SH][HPITCH];   // 18.1 KB
    __shared__ float wsum[BLOCK / 64];

    const int tid = threadIdx.x;
    const int x0 = blockIdx.x * TW;
    const int y0 = blockIdx.y * TH;
    const size_t base = (size_t)blockIdx.z * (size_t)(IMG_H * IMG_W);
    const float* pb = pred + base;
    const float* yb = yin + base;

    const bool interior = (x0 >= 8) && (x0 + TW + 8 <= IMG_W) &&
                          (y0 >= 5) && (y0 + TH + 5 <= IMG_H);

    const int vc  = tid & 31;
    const int vr0 = (tid >> 5) << 2;

    // ---------------- Phase A: mu channels (p, q) ----------------
    for (int it = tid; it < SH * 8; it += BLOCK) {
        const int hr = it >> 3;
        const int c0 = (it & 7) << 2;
        const int gy = y0 + hr - 5;
        float p[14], q[14];

        if (interior) {
            const float* rp = pb + (size_t)gy * IMG_W + (x0 + c0 - 8);
            const float* rq = yb + (size_t)gy * IMG_W + (x0 + c0 - 8);
            p[0] = rp[3];
            *(float4*)(p + 1) = *(const float4*)(rp + 4);
            *(float4*)(p + 5) = *(const float4*)(rp + 8);
            *(float4*)(p + 9) = *(const float4*)(rp + 12);
            p[13] = rp[16];
            q[0] = rq[3];
            *(float4*)(q + 1) = *(const float4*)(rq + 4);
            *(float4*)(q + 5) = *(const float4*)(rq + 8);
            *(float4*)(q + 9) = *(const float4*)(rq + 12);
            q[13] = rq[16];
        } else {
            if (gy >= 0 && gy < IMG_H) {
                const float* rowp = pb + (size_t)gy * IMG_W;
                const float* rowq = yb + (size_t)gy * IMG_W;
                #pragma unroll
                for (int k = 0; k < 14; ++k) {
                    const int gx = x0 + c0 - 5 + k;
                    const bool in = (gx >= 0) && (gx < IMG_W);
                    p[k] = in ? rowp[gx] : 0.f;
                    q[k] = in ? rowq[gx] : 0.f;
                }
            } else {
                #pragma unroll
                for (int k = 0; k < 14; ++k) { p[k] = 0.f; q[k] = 0.f; }
            }
        }

        // transposed accumulation: no temp arrays, weights constant-fold
        {
            float a0 = 0.f, a1 = 0.f, a2 = 0.f, a3 = 0.f;
            #pragma unroll
            for (int k = 0; k < 14; ++k) {
                const float v = p[k];
                if (k <= 10)           a0 += GW[k]     * v;
                if (k >= 1 && k <= 11) a1 += GW[k - 1] * v;
                if (k >= 2 && k <= 12) a2 += GW[k - 2] * v;
                if (k >= 3)            a3 += GW[k - 3] * v;
            }
            *(float4*)&Hb[0][hr][c0] = make_float4(a0, a1, a2, a3);
        }
        {
            float a0 = 0.f, a1 = 0.f, a2 = 0.f, a3 = 0.f;
            #pragma unroll
            for (int k = 0; k < 14; ++k) {
                const float v = q[k];
                if (k <= 10)           a0 += GW[k]     * v;
                if (k >= 1 && k <= 11) a1 += GW[k - 1] * v;
                if (k >= 2 && k <= 12) a2 += GW[k - 2] * v;
                if (k >= 3)            a3 += GW[k - 3] * v;
            }
            *(float4*)&Hb[1][hr][c0] = make_float4(a0, a1, a2, a3);
        }
    }
    __syncthreads();

    // ---- vertical pass A: mu1/mu2 kept in registers across phase B ----
    float mu1v[4], mu2v[4];
    {
        const float* hb0 = &Hb[0][vr0][vc];
        float a0 = 0.f, a1 = 0.f, a2 = 0.f, a3 = 0.f;
        #pragma unroll
        for (int k = 0; k < 14; ++k) {
            const float v = hb0[k * HPITCH];
            if (k <= 10)           a0 += GW[k]     * v;
            if (k >= 1 && k <= 11) a1 += GW[k - 1] * v;
            if (k >= 2 && k <= 12) a2 += GW[k - 2] * v;
            if (k >= 3)            a3 += GW[k - 3] * v;
        }
        mu1v[0] = a0; mu1v[1] = a1; mu1v[2] = a2; mu1v[3] = a3;
        const float* hb1 = &Hb[1][vr0][vc];
        a0 = a1 = a2 = a3 = 0.f;
        #pragma unroll
        for (int k = 0; k < 14; ++k) {
            const float v = hb1[k * HPITCH];
            if (k <= 10)           a0 += GW[k]     * v;
            if (k >= 1 && k <= 11) a1 += GW[k - 1] * v;
            if (k >= 2 && k <= 12) a2 += GW[k - 2] * v;
            if (k >= 3)            a3 += GW[k - 3] * v;
        }
        mu2v[0] = a0; mu2v[1] = a1; mu2v[2] = a2; mu2v[3] = a3;
    }
    __syncthreads();   // Hb about to be overwritten

    // ---------------- Phase B: product channels (pp, qq, pq) ----------------
    for (int it = tid; it < SH * 8; it += BLOCK) {
        const int hr = it >> 3;
        const int c0 = (it & 7) << 2;
        const int gy = y0 + hr - 5;
        float p[14], q[14];

        if (interior) {
            const float* rp = pb + (size_t)gy * IMG_W + (x0 + c0 - 8);
            const float* rq = yb + (size_t)gy * IMG_W + (x0 + c0 - 8);
            p[0] = rp[3];
            *(float4*)(p + 1) = *(const float4*)(rp + 4);
            *(float4*)(p + 5) = *(const float4*)(rp + 8);
            *(float4*)(p + 9) = *(const float4*)(rp + 12);
            p[13] = rp[16];
            q[0] = rq[3];
            *(float4*)(q + 1) = *(const float4*)(rq + 4);
            *(float4*)(q + 5) = *(const float4*)(rq + 8);
            *(float4*)(q + 9) = *(const float4*)(rq + 12);
            q[13] = rq[16];
        } else {
            if (gy >= 0 && gy < IMG_H) {
                const float* rowp = pb + (size_t)gy * IMG_W;
                const float* rowq = yb + (size_t)gy * IMG_W;
                #pragma unroll
                for (int k = 0; k < 14; ++k) {
                    const int gx = x0 + c0 - 5 + k;
                    const bool in = (gx >= 0) && (gx < IMG_W);
                    p[k] = in ? rowp[gx] : 0.f;
                    q[k] = in ? rowq[gx] : 0.f;
                }
            } else {
                #pragma unroll
                for (int k = 0; k < 14; ++k) { p[k] = 0.f; q[k] = 0.f; }
            }
        }

        // channel pp
        {
            float a0 = 0.f, a1 = 0.f, a2 = 0.f, a3 = 0.f;
            #pragma unroll
            for (int k = 0; k < 14; ++k) {
                const float v = p[k] * p[k];
                if (k <= 10)           a0 += GW[k]     * v;
                if (k >= 1 && k <= 11) a1 += GW[k - 1] * v;
                if (k >= 2 && k <= 12) a2 += GW[k - 2] * v;
                if (k >= 3)            a3 += GW[k - 3] * v;
            }
            *(float4*)&Hb[0][hr][c0] = make_float4(a0, a1, a2, a3);
        }
        // channel qq
        {
            float a0 = 0.f, a1 = 0.f, a2 = 0.f, a3 = 0.f;
            #pragma unroll
            for (int k = 0; k < 14; ++k) {
                const float v = q[k] * q[k];
                if (k <= 10)           a0 += GW[k]     * v;
                if (k >= 1 && k <= 11) a1 += GW[k - 1] * v;
                if (k >= 2 && k <= 12) a2 += GW[k - 2] * v;
                if (k >= 3)            a3 += GW[k - 3] * v;
            }
            *(float4*)&Hb[1][hr][c0] = make_float4(a0, a1, a2, a3);
        }
        // channel pq
        {
            float a0 = 0.f, a1 = 0.f, a2 = 0.f, a3 = 0.f;
            #pragma unroll
            for (int k = 0; k < 14; ++k) {
                const float v = p[k] * q[k];
                if (k <= 10)           a0 += GW[k]     * v;
                if (k >= 1 && k <= 11) a1 += GW[k - 1] * v;
                if (k >= 2 && k <= 12) a2 += GW[k - 2] * v;
                if (k >= 3)            a3 += GW[k - 3] * v;
            }
            *(float4*)&Hb[2][hr][c0] = make_float4(a0, a1, a2, a3);
        }
    }
    __syncthreads();

    // ---------------- vertical pass B + SSIM epilogue ----------------
    const float C1f = 1e-4f;
    const float C2f = 9e-4f;
    float lsum = 0.f;
    {
        float m11v[4], m22v[4], m12v[4];
        #pragma unroll
        for (int ch = 0; ch < 3; ++ch) {
            const float* hb = &Hb[ch][vr0][vc];
            float a0 = 0.f, a1 = 0.f, a2 = 0.f, a3 = 0.f;
            #pragma unroll
            for (int k = 0; k < 14; ++k) {
                const float v = hb[k * HPITCH];
                if (k <= 10)           a0 += GW[k]     * v;
                if (k >= 1 && k <= 11) a1 += GW[k - 1] * v;
                if (k >= 2 && k <= 12) a2 += GW[k - 2] * v;
                if (k >= 3)            a3 += GW[k - 3] * v;
            }
            float* dst = (ch == 0) ? m11v : (ch == 1) ? m22v : m12v;
            dst[0] = a0; dst[1] = a1; dst[2] = a2; dst[3] = a3;
        }

        #pragma unroll
        for (int o = 0; o < 4; ++o) {
            float mu1 = mu1v[o], mu2 = mu2v[o];
            float mu1s = mu1 * mu1;
            float mu2s = mu2 * mu2;
            float mu12 = mu1 * mu2;
            float s1  = m11v[o] - mu1s;
            float s2  = m22v[o] - mu2s;
            float s12 = m12v[o] - mu12;
            float num = (2.f * mu12 + C1f) * (2.f * s12 + C2f) * (s12 + 0.5f * C2f);
            float den = (mu1s + mu2s + C1f) * (s1 + s2 + C2f) *
                        (__builtin_amdgcn_sqrtf(s1 * s2) + 0.5f * C2f);
            lsum += num * __builtin_amdgcn_rcpf(den);
        }
    }

    // ---- block reduction, plain partial store ----
    #pragma unroll
    for (int off = 32; off > 0; off >>= 1)
        lsum += __shfl_xor(lsum, off);
    const int wid  = tid >> 6;
    const int lane = tid & 63;
    if (lane == 0) wsum[wid] = lsum;
    __syncthreads();
    if (tid == 0) {
        const int bid = (blockIdx.z * GY_ + blockIdx.y) * GX_ + blockIdx.x;
        partial[bid] = wsum[0] + wsum[1] + wsum[2] + wsum[3];
    }
}

// ---------------------------------------------------------------------------
// Deterministic final reduction in double (fixed assignment + order).
// ---------------------------------------------------------------------------
__global__ __launch_bounds__(1024) void ssim_reduce_kernel(
    const float* __restrict__ partial, float* __restrict__ out)
{
    __shared__ double sd[1024];
    double s = 0.0;
    const float4* p4 = (const float4*)partial;      // NBLOCKS % 4 == 0
    for (int i = threadIdx.x; i < NBLOCKS / 4; i += 1024) {
        float4 v = p4[i];
        s += (double)v.x + (double)v.y + (double)v.z + (double)v.w;
    }
    sd[threadIdx.x] = s;
    __syncthreads();
    #pragma unroll
    for (int st = 512; st > 0; st >>= 1) {
        if (threadIdx.x < st) sd[threadIdx.x] += sd[threadIdx.x + st];
        __syncthreads();
    }
    if (threadIdx.x == 0)
        out[0] = (float)(sd[0] * (1.0 / ((double)IMG_B * IMG_H * IMG_W)));
}

extern "C" void kernel_launch(void* const* d_in, const int* in_sizes, int n_in,
                              void* d_out, int out_size, void* d_ws, size_t ws_size,
                              hipStream_t stream)
{
    const float* pred = (const float*)d_in[0];
    const float* yin  = (const float*)d_in[1];
    float* out     = (float*)d_out;
    float* partial = (float*)d_ws;

    dim3 grid(GX_, GY_, IMG_B);   // 24 x 24 x 32
    ssim_tile_kernel<<<grid, BLOCK, 0, stream>>>(pred, yin, partial);
    ssim_reduce_kernel<<<1, 1024, 0, stream>>>(partial, out);
}

// Round 9
// 230.535 us; speedup vs baseline: 2.0267x; 2.0267x over previous
//
#include <hip/hip_runtime.h>

typedef float f32x2 __attribute__((ext_vector_type(2)));

#define TW 32
#define TH 32
#define SH 42              // TH + 10 halo rows
#define PITCH2 34          // f32x2 pitch for paired planes (even -> 16B rows; 4-bank row shift)
#define HPITCH 36          // scalar pitch for pq plane
#define BLOCK 256
#define IMG_W 768
#define IMG_H 768
#define IMG_B 32
#define GX_ (IMG_W / TW)
#define GY_ (IMG_H / TH)
#define NBLOCKS (GX_ * GY_ * IMG_B)   // 18432

// Gaussian window sigma=1.5, ws=11, normalized (f64-computed, f32-cast).
#define W0 0.00102838f
#define W1 0.00759876f
#define W2 0.03600077f
#define W3 0.10936069f
#define W4 0.21300554f
#define W5 0.26601173f

__device__ __forceinline__ f32x2 sp2(float s) { f32x2 v; v.x = s; v.y = s; return v; }

// R4 structure (known-good: 143us, no spill) + packed-f32 math.
// (256,5): 102-VGPR budget — do NOT tighten; <=64 caps provoke wholesale
// array spill (R5/R6/R7: 370-500 MB scratch traffic).
__global__ __launch_bounds__(BLOCK, 5) void ssim_tile_kernel(
    const float* __restrict__ pred, const float* __restrict__ yin,
    float* __restrict__ partial)
{
    constexpr float GW[11] = {W0, W1, W2, W3, W4, W5, W4, W3, W2, W1, W0};

    __shared__ __align__(16) f32x2 Hmu[SH][PITCH2];   // {mu1h, mu2h}   11.4 KB
    __shared__ __align__(16) f32x2 Hsq[SH][PITCH2];   // {pph, qqh}     11.4 KB
    __shared__ __align__(16) float Hpq[SH][HPITCH];   // pqh             6.0 KB
    __shared__ float wsum[BLOCK / 64];

    const int tid = threadIdx.x;
    const int x0 = blockIdx.x * TW;
    const int y0 = blockIdx.y * TH;
    const size_t base = (size_t)blockIdx.z * (size_t)(IMG_H * IMG_W);
    const float* pb = pred + base;
    const float* yb = yin + base;

    const bool interior = (x0 >= 8) && (x0 + TW + 8 <= IMG_W) &&
                          (y0 >= 5) && (y0 + TH + 5 <= IMG_H);

    // ---- horizontal pass: 42 rows x 8 col-groups (4 outputs each) ----
    for (int it = tid; it < SH * 8; it += BLOCK) {
        const int hr = it >> 3;
        const int c0 = (it & 7) << 2;
        const int gy = y0 + hr - 5;
        float p[14], q[14];

        if (interior) {
            const float* rp = pb + (size_t)gy * IMG_W + (x0 + c0 - 8);
            const float* rq = yb + (size_t)gy * IMG_W + (x0 + c0 - 8);
            p[0] = rp[3];
            *(float4*)(p + 1) = *(const float4*)(rp + 4);
            *(float4*)(p + 5) = *(const float4*)(rp + 8);
            *(float4*)(p + 9) = *(const float4*)(rp + 12);
            p[13] = rp[16];
            q[0] = rq[3];
            *(float4*)(q + 1) = *(const float4*)(rq + 4);
            *(float4*)(q + 5) = *(const float4*)(rq + 8);
            *(float4*)(q + 9) = *(const float4*)(rq + 12);
            q[13] = rq[16];
        } else {
            if (gy >= 0 && gy < IMG_H) {
                const float* rowp = pb + (size_t)gy * IMG_W;
                const float* rowq = yb + (size_t)gy * IMG_W;
                #pragma unroll
                for (int k = 0; k < 14; ++k) {
                    const int gx = x0 + c0 - 5 + k;
                    const bool in = (gx >= 0) && (gx < IMG_W);
                    p[k] = in ? rowp[gx] : 0.f;
                    q[k] = in ? rowq[gx] : 0.f;
                }
            } else {
                #pragma unroll
                for (int k = 0; k < 14; ++k) { p[k] = 0.f; q[k] = 0.f; }
            }
        }

        // pack channels: d[k] = {p[k], q[k]} -> v_pk_* does both at once
        f32x2 d[14];
        #pragma unroll
        for (int k = 0; k < 14; ++k) { f32x2 t; t.x = p[k]; t.y = q[k]; d[k] = t; }

        // mu channels (packed), transposed accumulation
        {
            f32x2 a0 = sp2(0.f), a1 = sp2(0.f), a2 = sp2(0.f), a3 = sp2(0.f);
            #pragma unroll
            for (int k = 0; k < 14; ++k) {
                const f32x2 v = d[k];
                if (k <= 10)           a0 += sp2(GW[k])     * v;
                if (k >= 1 && k <= 11) a1 += sp2(GW[k - 1]) * v;
                if (k >= 2 && k <= 12) a2 += sp2(GW[k - 2]) * v;
                if (k >= 3)            a3 += sp2(GW[k - 3]) * v;
            }
            Hmu[hr][c0]     = a0;
            Hmu[hr][c0 + 1] = a1;
            Hmu[hr][c0 + 2] = a2;
            Hmu[hr][c0 + 3] = a3;
        }
        // squared channels (packed)
        {
            f32x2 a0 = sp2(0.f), a1 = sp2(0.f), a2 = sp2(0.f), a3 = sp2(0.f);
            #pragma unroll
            for (int k = 0; k < 14; ++k) {
                const f32x2 v = d[k] * d[k];       // v_pk_mul: {p2, q2}
                if (k <= 10)           a0 += sp2(GW[k])     * v;
                if (k >= 1 && k <= 11) a1 += sp2(GW[k - 1]) * v;
                if (k >= 2 && k <= 12) a2 += sp2(GW[k - 2]) * v;
                if (k >= 3)            a3 += sp2(GW[k - 3]) * v;
            }
            Hsq[hr][c0]     = a0;
            Hsq[hr][c0 + 1] = a1;
            Hsq[hr][c0 + 2] = a2;
            Hsq[hr][c0 + 3] = a3;
        }
        // cross channel (scalar)
        {
            float a0 = 0.f, a1 = 0.f, a2 = 0.f, a3 = 0.f;
            #pragma unroll
            for (int k = 0; k < 14; ++k) {
                const float v = d[k].x * d[k].y;
                if (k <= 10)           a0 += GW[k]     * v;
                if (k >= 1 && k <= 11) a1 += GW[k - 1] * v;
                if (k >= 2 && k <= 12) a2 += GW[k - 2] * v;
                if (k >= 3)            a3 += GW[k - 3] * v;
            }
            *(float4*)&Hpq[hr][c0] = make_float4(a0, a1, a2, a3);
        }
    }
    __syncthreads();

    // ---- vertical pass: thread = 4 adjacent rows x 1 col ----
    const int vc  = tid & 31;
    const int vr0 = (tid >> 5) << 2;

    f32x2 MU0, MU1, MU2, MU3, SQ0, SQ1, SQ2, SQ3;
    float PQ0, PQ1, PQ2, PQ3;
    {
        f32x2 a0 = sp2(0.f), a1 = sp2(0.f), a2 = sp2(0.f), a3 = sp2(0.f);
        #pragma unroll
        for (int k = 0; k < 14; ++k) {
            const f32x2 v = Hmu[vr0 + k][vc];
            if (k <= 10)           a0 += sp2(GW[k])     * v;
            if (k >= 1 && k <= 11) a1 += sp2(GW[k - 1]) * v;
            if (k >= 2 && k <= 12) a2 += sp2(GW[k - 2]) * v;
            if (k >= 3)            a3 += sp2(GW[k - 3]) * v;
        }
        MU0 = a0; MU1 = a1; MU2 = a2; MU3 = a3;
    }
    {
        f32x2 a0 = sp2(0.f), a1 = sp2(0.f), a2 = sp2(0.f), a3 = sp2(0.f);
        #pragma unroll
        for (int k = 0; k < 14; ++k) {
            const f32x2 v = Hsq[vr0 + k][vc];
            if (k <= 10)           a0 += sp2(GW[k])     * v;
            if (k >= 1 && k <= 11) a1 += sp2(GW[k - 1]) * v;
            if (k >= 2 && k <= 12) a2 += sp2(GW[k - 2]) * v;
            if (k >= 3)            a3 += sp2(GW[k - 3]) * v;
        }
        SQ0 = a0; SQ1 = a1; SQ2 = a2; SQ3 = a3;
    }
    {
        float a0 = 0.f, a1 = 0.f, a2 = 0.f, a3 = 0.f;
        #pragma unroll
        for (int k = 0; k < 14; ++k) {
            const float v = Hpq[vr0 + k][vc];
            if (k <= 10)           a0 += GW[k]     * v;
            if (k >= 1 && k <= 11) a1 += GW[k - 1] * v;
            if (k >= 2 && k <= 12) a2 += GW[k - 2] * v;
            if (k >= 3)            a3 += GW[k - 3] * v;
        }
        PQ0 = a0; PQ1 = a1; PQ2 = a2; PQ3 = a3;
    }

    // ---- SSIM epilogue (partially packed) ----
    const float C1f = 1e-4f;
    const float C2f = 9e-4f;
    float lsum = 0.f;
    #pragma unroll
    for (int o = 0; o < 4; ++o) {
        const f32x2 mu = (o == 0) ? MU0 : (o == 1) ? MU1 : (o == 2) ? MU2 : MU3;
        const f32x2 sq = (o == 0) ? SQ0 : (o == 1) ? SQ1 : (o == 2) ? SQ2 : SQ3;
        const float pq = (o == 0) ? PQ0 : (o == 1) ? PQ1 : (o == 2) ? PQ2 : PQ3;
        const f32x2 musq = mu * mu;            // {mu1^2, mu2^2}
        const float mu12 = mu.x * mu.y;
        const f32x2 sig  = sq - musq;          // {s1, s2}
        const float s12  = pq - mu12;
        const float num = (2.f * mu12 + C1f) * (2.f * s12 + C2f) * (s12 + 0.5f * C2f);
        const float den = (musq.x + musq.y + C1f) * (sig.x + sig.y + C2f) *
                          (__builtin_amdgcn_sqrtf(sig.x * sig.y) + 0.5f * C2f);
        lsum += num * __builtin_amdgcn_rcpf(den);
    }

    // ---- block reduction, plain partial store ----
    #pragma unroll
    for (int off = 32; off > 0; off >>= 1)
        lsum += __shfl_xor(lsum, off);
    const int wid  = tid >> 6;
    const int lane = tid & 63;
    if (lane == 0) wsum[wid] = lsum;
    __syncthreads();
    if (tid == 0) {
        const int bid = (blockIdx.z * GY_ + blockIdx.y) * GX_ + blockIdx.x;
        partial[bid] = wsum[0] + wsum[1] + wsum[2] + wsum[3];
    }
}

// ---------------------------------------------------------------------------
// Deterministic final reduction in double (fixed assignment + order).
// ---------------------------------------------------------------------------
__global__ __launch_bounds__(1024) void ssim_reduce_kernel(
    const float* __restrict__ partial, float* __restrict__ out)
{
    __shared__ double sd[1024];
    double s = 0.0;
    const float4* p4 = (const float4*)partial;      // NBLOCKS % 4 == 0
    for (int i = threadIdx.x; i < NBLOCKS / 4; i += 1024) {
        float4 v = p4[i];
        s += (double)v.x + (double)v.y + (double)v.z + (double)v.w;
    }
    sd[threadIdx.x] = s;
    __syncthreads();
    #pragma unroll
    for (int st = 512; st > 0; st >>= 1) {
        if (threadIdx.x < st) sd[threadIdx.x] += sd[threadIdx.x + st];
        __syncthreads();
    }
    if (threadIdx.x == 0)
        out[0] = (float)(sd[0] * (1.0 / ((double)IMG_B * IMG_H * IMG_W)));
}

extern "C" void kernel_launch(void* const* d_in, const int* in_sizes, int n_in,
                              void* d_out, int out_size, void* d_ws, size_t ws_size,
                              hipStream_t stream)
{
    const float* pred = (const float*)d_in[0];
    const float* yin  = (const float*)d_in[1];
    float* out     = (float*)d_out;
    float* partial = (float*)d_ws;

    dim3 grid(GX_, GY_, IMG_B);   // 24 x 24 x 32
    ssim_tile_kernel<<<grid, BLOCK, 0, stream>>>(pred, yin, partial);
    ssim_reduce_kernel<<<1, 1024, 0, stream>>>(partial, out);
}